// Round 5
// baseline (717.025 us; speedup 1.0000x reference)
//
#include <hip/hip_runtime.h>

#define BATCH 16384
#define RT    32        // batch rows per block -> 512 blocks -> 2 blocks/CU

typedef unsigned short u16;
typedef __attribute__((ext_vector_type(8))) short short8;
typedef __attribute__((ext_vector_type(4))) short short4v;
typedef __attribute__((ext_vector_type(4))) float f32x4;

// ---------- bf16 split helpers ----------
__device__ __forceinline__ u16 f2bf(float x) {
    union { float f; unsigned int u; } a; a.f = x;
    unsigned int r = a.u + 0x7fffu + ((a.u >> 16) & 1u);   // RTN-even
    return (u16)(r >> 16);
}
__device__ __forceinline__ float bf2f(u16 h) {
    union { unsigned int u; float f; } a; a.u = ((unsigned int)h) << 16;
    return a.f;
}

// ================= weight pre-pack kernels =================
// MFMA fragment pack: P[(v*KG + (k>>3))*N + n][k&7] (contiguous 16B frags).
// STRICT premask: only parents k <= v-2 go through MFMA; the newest possible
// parent k = v-1 is applied in-kernel as a rank-1 VALU update (so the Y-tile
// column v-1 may be finalized lazily without an extra barrier).
__global__ void prep_w1(const float* __restrict__ W1, const int* __restrict__ G,
                        u16* __restrict__ Ph, u16* __restrict__ Pl) {
    int idx = blockIdx.x * 256 + threadIdx.x;   // 64*64*256 exactly
    int n = idx & 255;
    int k = (idx >> 8) & 63;
    int v = idx >> 14;
    float w = (k + 1 < v && G[k * 64 + v] > 0) ? W1[((size_t)v * 65 + k) * 256 + n] : 0.0f;
    u16 h = f2bf(w);
    u16 l = f2bf(w - bf2f(h));
    size_t o = (((size_t)(v * 8 + (k >> 3)) * 256 + n) << 3) + (k & 7);
    Ph[o] = h; Pl[o] = l;
}
__global__ void prep_w2(const float* __restrict__ W2, u16* __restrict__ Ph,
                        u16* __restrict__ Pl) {
    int idx = blockIdx.x * 256 + threadIdx.x;   // 64*256*128 exactly
    int n = idx & 127;
    int k = (idx >> 7) & 255;
    int v = idx >> 15;
    float w = W2[((size_t)v * 256 + k) * 128 + n];
    u16 h = f2bf(w);
    u16 l = f2bf(w - bf2f(h));
    size_t o = (((size_t)(v * 32 + (k >> 3)) * 128 + n) << 3) + (k & 7);
    Ph[o] = h; Pl[o] = l;
}

// ================= persistent fused kernel =================
// XOR-swizzled LDS (T2): byte ^= (row&7)<<4
__device__ __forceinline__ int a_byte(int row, int colx2) {   // A: stride 64 u16
    return (row * 128 + colx2) ^ ((row & 7) << 4);
}
__device__ __forceinline__ int h_byte(int row, int colx2) {   // h1: stride 256 u16
    return (row * 512 + colx2) ^ ((row & 7) << 4);
}
#define UST 68   // U-tile stride (floats): 16B-aligned rows, 4-bank row skew

__global__ __launch_bounds__(512, 4)
void sen_fused(const float* __restrict__ U, const int* __restrict__ G,
               const u16* __restrict__ P1h, const u16* __restrict__ P1l,
               const u16* __restrict__ P2h, const u16* __restrict__ P2l,
               const float* __restrict__ W1, const float* __restrict__ b1,
               const float* __restrict__ b2, const float* __restrict__ W3,
               const float* __restrict__ b3, float* __restrict__ Y)
{
    __shared__ __attribute__((aligned(16))) u16 Ah[RT * 64];
    __shared__ __attribute__((aligned(16))) u16 Al[RT * 64];
    __shared__ __attribute__((aligned(16))) u16 h1h[RT * 256];
    __shared__ __attribute__((aligned(16))) u16 h1l[RT * 256];
    __shared__ __attribute__((aligned(16))) float Ut[RT * UST];
    __shared__ float yp[8][RT];      // layer-3 partials, one slot per wave
    __shared__ float b3s[64];
    __shared__ float gm[64];         // gm[v] = (v>0 && G[v-1][v]>0)

    const int tid  = threadIdx.x;
    const int row0 = blockIdx.x * RT;

    // ---- one-time staging: zero Y tile, U tile, b3, newest-parent mask ----
    {
        short8 z = {0,0,0,0,0,0,0,0};
        for (int i = tid; i < (RT * 64) / 8; i += 512) {
            *(short8*)&Ah[i * 8] = z;
            *(short8*)&Al[i * 8] = z;
        }
        const int row = tid >> 4, c4 = (tid & 15) * 4;
        *(f32x4*)&Ut[row * UST + c4] = *(const f32x4*)(U + (size_t)(row0 + row) * 64 + c4);
        if (tid < 64) {
            b3s[tid] = b3[tid];
            gm[tid]  = (tid > 0 && G[(tid - 1) * 64 + tid] > 0) ? 1.0f : 0.0f;
        }
    }
    __syncthreads();

    const int w  = tid >> 6, l = tid & 63;
    const int lr = l & 15,  lk = l >> 4;
    const int mg = w;   // phase 1: dim group (32 dims each)
    const int cg = w;   // phase 2: col group (16 cols each)

    #pragma unroll 1
    for (int v = 0; v < 64; ++v) {
        // ======== prologue (pre-B1): params, y_{v-1}, lazy finalize ========
        f32x4 b1v[2], w64v[2], w1pv[2];
        #pragma unroll
        for (int ni = 0; ni < 2; ++ni) {
            const int dim = mg * 32 + ni * 16 + lk * 4;
            b1v[ni]  = *(const f32x4*)(b1 + v * 256 + dim);
            w64v[ni] = *(const f32x4*)(W1 + ((size_t)v * 65 + 64) * 256 + dim);
        }
        const float b2c = b2[v * 128 + cg * 16 + lr];
        const float w3c = W3[v * 128 + cg * 16 + lr];
        float u_c[2], ycol[2] = {0.f, 0.f};
        #pragma unroll
        for (int nj = 0; nj < 2; ++nj)
            u_c[nj] = Ut[(nj * 16 + lr) * UST + v];

        if (v > 0) {
            const float g = gm[v];
            #pragma unroll
            for (int ni = 0; ni < 2; ++ni) {
                const int dim = mg * 32 + ni * 16 + lk * 4;
                f32x4 t = *(const f32x4*)(W1 + ((size_t)v * 65 + (v - 1)) * 256 + dim);
                w1pv[ni] = (f32x4){t[0] * g, t[1] * g, t[2] * g, t[3] * g};
            }
            #pragma unroll
            for (int nj = 0; nj < 2; ++nj) {
                float y = b3s[v - 1];
                #pragma unroll
                for (int c = 0; c < 8; ++c) y += yp[c][nj * 16 + lr];
                ycol[nj] = y;
            }
            // lazy finalize of Y-tile column v-1 (fenced by B1; concurrent
            // phase-1 reads of this column hit a ZERO weight -> harmless)
            if (w == 0 && lk == 0) {
                #pragma unroll
                for (int nj = 0; nj < 2; ++nj) {
                    const int row = nj * 16 + lr;
                    u16 h = f2bf(ycol[nj]);
                    Ah[a_byte(row, (v - 1) * 2) >> 1] = h;
                    Al[a_byte(row, (v - 1) * 2) >> 1] = f2bf(ycol[nj] - bf2f(h));
                }
            }
        } else {
            w1pv[0] = w1pv[1] = (f32x4){0.f, 0.f, 0.f, 0.f};
        }

        // ======== Phase 1 — layer 1 (operand-swapped, strict mask) ========
        f32x4 acc1[2][2];
        #pragma unroll
        for (int nj = 0; nj < 2; ++nj)
            #pragma unroll
            for (int ni = 0; ni < 2; ++ni) acc1[nj][ni] = (f32x4){0.f, 0.f, 0.f, 0.f};

        #pragma unroll
        for (int kt = 0; kt < 2; ++kt) {
            short8 Yfh[2], Yfl[2];
            #pragma unroll
            for (int nj = 0; nj < 2; ++nj) {
                const int bo = a_byte(nj * 16 + lr, kt * 64 + lk * 16);
                Yfh[nj] = *(const short8*)&Ah[bo >> 1];
                Yfl[nj] = *(const short8*)&Al[bo >> 1];
            }
            #pragma unroll
            for (int ni = 0; ni < 2; ++ni) {
                const size_t off = (((size_t)(v * 8 + kt * 4 + lk) * 256) + mg * 32 + ni * 16 + lr) << 3;
                const short8 Wh = *(const short8*)&P1h[off];
                const short8 Wl = *(const short8*)&P1l[off];
                #pragma unroll
                for (int nj = 0; nj < 2; ++nj) {
                    acc1[nj][ni] = __builtin_amdgcn_mfma_f32_16x16x32_bf16(Wh, Yfh[nj], acc1[nj][ni], 0, 0, 0);
                    acc1[nj][ni] = __builtin_amdgcn_mfma_f32_16x16x32_bf16(Wh, Yfl[nj], acc1[nj][ni], 0, 0, 0);
                    acc1[nj][ni] = __builtin_amdgcn_mfma_f32_16x16x32_bf16(Wl, Yfh[nj], acc1[nj][ni], 0, 0, 0);
                }
            }
        }
        // epilogue: + bias + u*W1[64,:] + y_{v-1}*W1[v-1,:], relu, split, store
        #pragma unroll
        for (int nj = 0; nj < 2; ++nj) {
            const int brow = nj * 16 + lr;
            #pragma unroll
            for (int ni = 0; ni < 2; ++ni) {
                short4v ph, pl;
                #pragma unroll
                for (int r = 0; r < 4; ++r) {
                    float x = acc1[nj][ni][r] + b1v[ni][r]
                            + u_c[nj] * w64v[ni][r] + ycol[nj] * w1pv[ni][r];
                    x = fmaxf(x, 0.0f);
                    u16 h = f2bf(x);
                    ph[r] = (short)h;
                    pl[r] = (short)f2bf(x - bf2f(h));
                }
                const int bo = h_byte(brow, mg * 64 + ni * 32 + lk * 8);
                *(short4v*)&h1h[bo >> 1] = ph;
                *(short4v*)&h1l[bo >> 1] = pl;
            }
        }
        __syncthreads();   // B1: h1 + A-col(v-1) visible

        // ======== Phase 2 — layer 2 + in-register layer 3 ========
        f32x4 acc2[2];
        acc2[0] = (f32x4){0.f, 0.f, 0.f, 0.f};
        acc2[1] = (f32x4){0.f, 0.f, 0.f, 0.f};
        #pragma unroll
        for (int kt = 0; kt < 8; ++kt) {
            short8 Hfh[2], Hfl[2];
            #pragma unroll
            for (int mi = 0; mi < 2; ++mi) {
                const int bo = h_byte(mi * 16 + lr, kt * 64 + lk * 16);
                Hfh[mi] = *(const short8*)&h1h[bo >> 1];
                Hfl[mi] = *(const short8*)&h1l[bo >> 1];
            }
            const size_t off = (((size_t)(v * 32 + kt * 4 + lk) * 128) + cg * 16 + lr) << 3;
            const short8 Bh = *(const short8*)&P2h[off];
            const short8 Bl = *(const short8*)&P2l[off];
            #pragma unroll
            for (int mi = 0; mi < 2; ++mi) {
                acc2[mi] = __builtin_amdgcn_mfma_f32_16x16x32_bf16(Hfh[mi], Bh, acc2[mi], 0, 0, 0);
                acc2[mi] = __builtin_amdgcn_mfma_f32_16x16x32_bf16(Hfh[mi], Bl, acc2[mi], 0, 0, 0);
                acc2[mi] = __builtin_amdgcn_mfma_f32_16x16x32_bf16(Hfl[mi], Bh, acc2[mi], 0, 0, 0);
            }
        }
        // layer 3 partials: sum over this cg's 16 cols via shfl over lr
        f32x4 sv[2];
        #pragma unroll
        for (int mi = 0; mi < 2; ++mi)
            #pragma unroll
            for (int r = 0; r < 4; ++r) {
                float t = fmaxf(acc2[mi][r] + b2c, 0.0f) * w3c;
                t += __shfl_xor(t, 1);
                t += __shfl_xor(t, 2);
                t += __shfl_xor(t, 4);
                t += __shfl_xor(t, 8);
                sv[mi][r] = t;
            }
        if (lr == 0) {
            *(f32x4*)&yp[cg][lk * 4]      = sv[0];
            *(f32x4*)&yp[cg][16 + lk * 4] = sv[1];
        }
        __syncthreads();   // B2: yp visible; h1 free for next step
    }

    // ---- finalize column 63, then coalesced tile store ----
    if (w == 0 && lk == 0) {
        #pragma unroll
        for (int nj = 0; nj < 2; ++nj) {
            const int row = nj * 16 + lr;
            float y = b3s[63];
            #pragma unroll
            for (int c = 0; c < 8; ++c) y += yp[c][row];
            u16 h = f2bf(y);
            Ah[a_byte(row, 63 * 2) >> 1] = h;
            Al[a_byte(row, 63 * 2) >> 1] = f2bf(y - bf2f(h));
        }
    }
    __syncthreads();
    {
        const int row = tid >> 4, c4 = (tid & 15) * 4;
        const int bo = a_byte(row, c4 * 2);
        const short4v hv = *(const short4v*)&Ah[bo >> 1];
        const short4v lv = *(const short4v*)&Al[bo >> 1];
        float4 o;
        o.x = bf2f((u16)hv[0]) + bf2f((u16)lv[0]);
        o.y = bf2f((u16)hv[1]) + bf2f((u16)lv[1]);
        o.z = bf2f((u16)hv[2]) + bf2f((u16)lv[2]);
        o.w = bf2f((u16)hv[3]) + bf2f((u16)lv[3]);
        *(float4*)(Y + (size_t)(row0 + row) * 64 + c4) = o;
    }
}

extern "C" void kernel_launch(void* const* d_in, const int* in_sizes, int n_in,
                              void* d_out, int out_size, void* d_ws, size_t ws_size,
                              hipStream_t stream) {
    // inputs: X, U, causal_graph, W1, b1, W2, b2, W3, b3  (X never feeds the recursion)
    const float* U  = (const float*)d_in[1];
    const int*   G  = (const int*)  d_in[2];
    const float* W1 = (const float*)d_in[3];
    const float* b1 = (const float*)d_in[4];
    const float* W2 = (const float*)d_in[5];
    const float* b2 = (const float*)d_in[6];
    const float* W3 = (const float*)d_in[7];
    const float* b3 = (const float*)d_in[8];
    float* Y = (float*)d_out;

    const size_t S1 = (size_t)64 * 64 * 256;     // u16 elements per W1 array
    const size_t S2 = (size_t)64 * 256 * 128;    // u16 elements per W2 array
    u16* P1h = (u16*)d_ws;
    u16* P1l = P1h + S1;
    u16* P2h = P1l + S1;
    u16* P2l = P2h + S2;

    prep_w1<<<(64 * 64 * 256) / 256, 256, 0, stream>>>(W1, G, P1h, P1l);
    prep_w2<<<(64 * 256 * 128) / 256, 256, 0, stream>>>(W2, P2h, P2l);
    sen_fused<<<BATCH / RT, 512, 0, stream>>>(U, G, P1h, P1l, P2h, P2l,
                                              W1, b1, b2, W3, b3, Y);
}

// Round 6
// 345.750 us; speedup vs baseline: 2.0738x; 2.0738x over previous
//
#include <hip/hip_runtime.h>

#define BATCH 16384
#define RT    32        // batch rows per block -> 512 blocks -> 2 blocks/CU

typedef unsigned short u16;
typedef __attribute__((ext_vector_type(8))) short short8;
typedef __attribute__((ext_vector_type(8))) _Float16 f16x8;
typedef __attribute__((ext_vector_type(4))) float f32x4;

// ---------- fp16 helpers (storage = u16 bit patterns) ----------
__device__ __forceinline__ u16 f2h(float x) {
    union { _Float16 h; u16 u; } c; c.h = (_Float16)x; return c.u;
}
__device__ __forceinline__ float h2f(u16 b) {
    union { u16 u; _Float16 h; } c; c.u = b; return (float)c.h;
}

// ================= weight pre-pack kernels (single fp16) =================
// MFMA fragment pack: P[(v*KG + (k>>3))*N + n][k&7] so one fragment
// (8 consecutive k at fixed n) is a contiguous 16B load.
// W1 pre-masked by the parent mask (strictly-upper G => masked-out columns
// are exactly the not-yet-computed Y columns, so the Y tile needs no mask).
__global__ void prep_w1(const float* __restrict__ W1, const int* __restrict__ G,
                        u16* __restrict__ P) {
    int idx = blockIdx.x * 256 + threadIdx.x;   // 64*64*256 exactly
    int n = idx & 255;
    int k = (idx >> 8) & 63;
    int v = idx >> 14;
    float w = (G[k * 64 + v] > 0) ? W1[((size_t)v * 65 + k) * 256 + n] : 0.0f;
    P[(((size_t)(v * 8 + (k >> 3)) * 256 + n) << 3) + (k & 7)] = f2h(w);
}
__global__ void prep_w2(const float* __restrict__ W2, u16* __restrict__ P) {
    int idx = blockIdx.x * 256 + threadIdx.x;   // 64*256*128 exactly
    int n = idx & 127;
    int k = (idx >> 7) & 255;
    int v = idx >> 15;
    P[(((size_t)(v * 32 + (k >> 3)) * 128 + n) << 3) + (k & 7)] =
        f2h(W2[((size_t)v * 256 + k) * 128 + n]);
}

// ================= persistent fused kernel =================
// One block = 32 batch rows, loops over all 64 variables. Y tile and h1
// live in XOR-swizzled LDS as fp16 hi/lo pairs (~40 KB -> 2 blocks/CU).
// Swizzle: byte ^= (row&7)<<4
__device__ __forceinline__ int a_byte(int row, int colx2) {   // A: stride 64 u16
    return (row * 128 + colx2) ^ ((row & 7) << 4);
}
__device__ __forceinline__ int h_byte(int row, int colx2) {   // h1: stride 256 u16
    return (row * 512 + colx2) ^ ((row & 7) << 4);
}

__global__ __launch_bounds__(512, 4)
void sen_fused(const float* __restrict__ U,
               const u16* __restrict__ P1, const u16* __restrict__ P2,
               const float* __restrict__ W1, const float* __restrict__ b1,
               const float* __restrict__ b2, const float* __restrict__ W3,
               const float* __restrict__ b3, float* __restrict__ Y)
{
    __shared__ __attribute__((aligned(16))) u16 Ah[RT * 64];
    __shared__ __attribute__((aligned(16))) u16 Al[RT * 64];
    __shared__ __attribute__((aligned(16))) u16 h1h[RT * 256];
    __shared__ __attribute__((aligned(16))) u16 h1l[RT * 256];

    const int tid  = threadIdx.x;
    const int row0 = blockIdx.x * RT;

    // zero Y tile (stale LDS bits could be NaN; NaN*0 = NaN in MFMA)
    {
        short8 z = {0,0,0,0,0,0,0,0};
        for (int i = tid; i < (RT * 64) / 8; i += 512) {
            *(short8*)&Ah[i * 8] = z;
            *(short8*)&Al[i * 8] = z;
        }
    }
    __syncthreads();

    const int w  = tid >> 6, l = tid & 63;
    const int lr = l & 15,  lk = l >> 4;
    const int mg = w;   // phase 1: dim group (32 dims each, W1 read once/block)
    const int cg = w;   // phase 2: col group (16 cols each, W2 read once/block)
    float* yp = (float*)h1h;   // [8][32] overlay, touched only while h1 is dead

    #pragma unroll 1
    for (int v = 0; v < 64; ++v) {
        // ---- per-step parameter prefetch (latency hides under phase-1 MFMAs) ----
        f32x4 b1v[2], w64v[2];
        #pragma unroll
        for (int ni = 0; ni < 2; ++ni) {
            const int dim = mg * 32 + ni * 16 + lk * 4;
            b1v[ni]  = *(const f32x4*)(b1 + v * 256 + dim);
            w64v[ni] = *(const f32x4*)(W1 + ((size_t)v * 65 + 64) * 256 + dim);
        }
        float u_c[2];
        #pragma unroll
        for (int nj = 0; nj < 2; ++nj)
            u_c[nj] = U[(size_t)(row0 + nj * 16 + lr) * 64 + v];
        const float b2c = b2[v * 128 + cg * 16 + lr];
        const float w3c = W3[v * 128 + cg * 16 + lr];

        // ======== Phase 1 — Layer 1 (operand-swapped): h1t[dim][brow] ========
        // wave: dims mg*32..+31 (ni=2) x all 32 rows (nj=2), K=64
        f32x4 acc1[2][2];
        #pragma unroll
        for (int nj = 0; nj < 2; ++nj)
            #pragma unroll
            for (int ni = 0; ni < 2; ++ni) acc1[nj][ni] = (f32x4){0.f, 0.f, 0.f, 0.f};

        #pragma unroll
        for (int kt = 0; kt < 2; ++kt) {
            f16x8 Yfh[2], Yfl[2];
            #pragma unroll
            for (int nj = 0; nj < 2; ++nj) {
                const int bo = a_byte(nj * 16 + lr, kt * 64 + lk * 16);
                Yfh[nj] = *(const f16x8*)&Ah[bo >> 1];
                Yfl[nj] = *(const f16x8*)&Al[bo >> 1];
            }
            #pragma unroll
            for (int ni = 0; ni < 2; ++ni) {
                const size_t off = (((size_t)(v * 8 + kt * 4 + lk) * 256) + mg * 32 + ni * 16 + lr) << 3;
                const f16x8 Wf = *(const f16x8*)&P1[off];
                #pragma unroll
                for (int nj = 0; nj < 2; ++nj) {
                    acc1[nj][ni] = __builtin_amdgcn_mfma_f32_16x16x32_f16(Wf, Yfh[nj], acc1[nj][ni], 0, 0, 0);
                    acc1[nj][ni] = __builtin_amdgcn_mfma_f32_16x16x32_f16(Wf, Yfl[nj], acc1[nj][ni], 0, 0, 0);
                }
            }
        }
        // epilogue: + bias + u * W1[64,:] (exact fp32), relu, fp16 hi/lo split
        #pragma unroll
        for (int nj = 0; nj < 2; ++nj) {
            const int brow = nj * 16 + lr;
            #pragma unroll
            for (int ni = 0; ni < 2; ++ni) {
                u16 ph[4], pl[4];
                #pragma unroll
                for (int r = 0; r < 4; ++r) {
                    float x = acc1[nj][ni][r] + b1v[ni][r] + u_c[nj] * w64v[ni][r];
                    x = fmaxf(x, 0.0f);
                    u16 h = f2h(x);
                    ph[r] = h;
                    pl[r] = f2h(x - h2f(h));
                }
                const int bo = h_byte(brow, mg * 64 + ni * 32 + lk * 8);
                *(unsigned long long*)&h1h[bo >> 1] =
                    (unsigned long long)ph[0] | ((unsigned long long)ph[1] << 16) |
                    ((unsigned long long)ph[2] << 32) | ((unsigned long long)ph[3] << 48);
                *(unsigned long long*)&h1l[bo >> 1] =
                    (unsigned long long)pl[0] | ((unsigned long long)pl[1] << 16) |
                    ((unsigned long long)pl[2] << 32) | ((unsigned long long)pl[3] << 48);
            }
        }
        __syncthreads();   // B1: h1 written -> phase 2 may read

        // ======== Phase 2 — Layer 2: h2[32][cg*16..+16], K=256 ========
        f32x4 acc2[2];
        acc2[0] = (f32x4){0.f, 0.f, 0.f, 0.f};
        acc2[1] = (f32x4){0.f, 0.f, 0.f, 0.f};
        #pragma unroll
        for (int kt = 0; kt < 8; ++kt) {
            f16x8 Hfh[2], Hfl[2];
            #pragma unroll
            for (int mi = 0; mi < 2; ++mi) {
                const int bo = h_byte(mi * 16 + lr, kt * 64 + lk * 16);
                Hfh[mi] = *(const f16x8*)&h1h[bo >> 1];
                Hfl[mi] = *(const f16x8*)&h1l[bo >> 1];
            }
            const size_t off = (((size_t)(v * 32 + kt * 4 + lk) * 128) + cg * 16 + lr) << 3;
            const f16x8 Bf = *(const f16x8*)&P2[off];
            #pragma unroll
            for (int mi = 0; mi < 2; ++mi) {
                acc2[mi] = __builtin_amdgcn_mfma_f32_16x16x32_f16(Hfh[mi], Bf, acc2[mi], 0, 0, 0);
                acc2[mi] = __builtin_amdgcn_mfma_f32_16x16x32_f16(Hfl[mi], Bf, acc2[mi], 0, 0, 0);
            }
        }
        // layer 3 partials in registers: sum over this cg's 16 cols via shfl
        float s[2][4];
        #pragma unroll
        for (int mi = 0; mi < 2; ++mi)
            #pragma unroll
            for (int r = 0; r < 4; ++r) {
                float t = fmaxf(acc2[mi][r] + b2c, 0.0f) * w3c;
                t += __shfl_xor(t, 1);
                t += __shfl_xor(t, 2);
                t += __shfl_xor(t, 4);
                t += __shfl_xor(t, 8);
                s[mi][r] = t;
            }
        __syncthreads();   // B2: all h1 reads done -> h1 region is dead

        // ======== Phase 3 — stash per-cg partials in dead h1 region ========
        if (lr == 0) {
            #pragma unroll
            for (int mi = 0; mi < 2; ++mi)
                #pragma unroll
                for (int r = 0; r < 4; ++r)
                    yp[cg * 32 + mi * 16 + lk * 4 + r] = s[mi][r];
        }
        __syncthreads();   // B3: partials visible

        // ======== Phase 4 — finalize y column into the Y tile ========
        if (tid < RT) {
            float y = b3[v];
            #pragma unroll
            for (int c = 0; c < 8; ++c) y += yp[c * 32 + tid];
            u16 h = f2h(y);
            Ah[a_byte(tid, v * 2) >> 1] = h;
            Al[a_byte(tid, v * 2) >> 1] = f2h(y - h2f(h));
        }
        __syncthreads();   // B4: Y col v visible for step v+1 (h1 free again)
    }

    // ---- final coalesced store (hi+lo reconstruct), 1 float4 per thread ----
    {
        const int row = tid >> 4, c4 = (tid & 15) * 4;
        const int bo = a_byte(row, c4 * 2);
        const u16* hv = &Ah[bo >> 1];
        const u16* lv = &Al[bo >> 1];
        float4 o;
        o.x = h2f(hv[0]) + h2f(lv[0]);
        o.y = h2f(hv[1]) + h2f(lv[1]);
        o.z = h2f(hv[2]) + h2f(lv[2]);
        o.w = h2f(hv[3]) + h2f(lv[3]);
        *(float4*)(Y + (size_t)(row0 + row) * 64 + c4) = o;
    }
}

extern "C" void kernel_launch(void* const* d_in, const int* in_sizes, int n_in,
                              void* d_out, int out_size, void* d_ws, size_t ws_size,
                              hipStream_t stream) {
    // inputs: X, U, causal_graph, W1, b1, W2, b2, W3, b3  (X never feeds the recursion)
    const float* U  = (const float*)d_in[1];
    const int*   G  = (const int*)  d_in[2];
    const float* W1 = (const float*)d_in[3];
    const float* b1 = (const float*)d_in[4];
    const float* W2 = (const float*)d_in[5];
    const float* b2 = (const float*)d_in[6];
    const float* W3 = (const float*)d_in[7];
    const float* b3 = (const float*)d_in[8];
    float* Y = (float*)d_out;

    const size_t S1 = (size_t)64 * 64 * 256;     // u16 elements, packed W1
    u16* P1 = (u16*)d_ws;
    u16* P2 = P1 + S1;

    prep_w1<<<(64 * 64 * 256) / 256, 256, 0, stream>>>(W1, G, P1);
    prep_w2<<<(64 * 256 * 128) / 256, 256, 0, stream>>>(W2, P2);
    sen_fused<<<BATCH / RT, 512, 0, stream>>>(U, P1, P2, W1, b1, b2, W3, b3, Y);
}

// Round 7
// 287.913 us; speedup vs baseline: 2.4904x; 1.2009x over previous
//
#include <hip/hip_runtime.h>

#define BATCH 16384
#define RT    32        // batch rows per block -> 512 blocks -> 2 blocks/CU

typedef unsigned short u16;
typedef __attribute__((ext_vector_type(8))) short short8;
typedef __attribute__((ext_vector_type(8))) _Float16 f16x8;
typedef __attribute__((ext_vector_type(4))) float f32x4;

// ---------- fp16 helpers (storage = u16 bit patterns) ----------
__device__ __forceinline__ u16 f2h(float x) {
    union { _Float16 h; u16 u; } c; c.h = (_Float16)x; return c.u;
}
__device__ __forceinline__ float h2f(u16 b) {
    union { u16 u; _Float16 h; } c; c.u = b; return (float)c.h;
}

// ================= weight pre-pack kernels (single fp16) =================
// MFMA fragment pack: P[(v*KG + (k>>3))*N + n][k&7] so one fragment
// (8 consecutive k at fixed n) is a contiguous 16B load.
// W1 pre-masked by the parent mask (strictly-upper G => masked-out columns
// are exactly the not-yet-computed Y columns, so the Y tile needs no mask).
__global__ void prep_w1(const float* __restrict__ W1, const int* __restrict__ G,
                        u16* __restrict__ P) {
    int idx = blockIdx.x * 256 + threadIdx.x;   // 64*64*256 exactly
    int n = idx & 255;
    int k = (idx >> 8) & 63;
    int v = idx >> 14;
    float w = (G[k * 64 + v] > 0) ? W1[((size_t)v * 65 + k) * 256 + n] : 0.0f;
    P[(((size_t)(v * 8 + (k >> 3)) * 256 + n) << 3) + (k & 7)] = f2h(w);
}
__global__ void prep_w2(const float* __restrict__ W2, u16* __restrict__ P) {
    int idx = blockIdx.x * 256 + threadIdx.x;   // 64*256*128 exactly
    int n = idx & 127;
    int k = (idx >> 7) & 255;
    int v = idx >> 15;
    P[(((size_t)(v * 32 + (k >> 3)) * 128 + n) << 3) + (k & 7)] =
        f2h(W2[((size_t)v * 256 + k) * 128 + n]);
}

// ================= persistent fused kernel =================
// One block = 32 batch rows, loops over all 64 variables.
// LDS: Y tile as fp16 hi/lo (recursion accuracy), h1 as SINGLE fp16
// (error analysis: h1 quant adds only ~1e-4 to y).
// Bank-conflict fix by PADDED strides: row stride % 128B == 16B, so
// consecutive rows start at consecutive 16B bank slots (no XOR, no
// aliasing with the lk column bits).
#define AST   72     // Y-tile stride (u16): 144B = 16 mod 128
#define H1ST  264    // h1 stride (u16): 528B = 16 mod 128

__global__ __launch_bounds__(512, 4)
void sen_fused(const float* __restrict__ U,
               const u16* __restrict__ P1, const u16* __restrict__ P2,
               const float* __restrict__ W1, const float* __restrict__ b1,
               const float* __restrict__ b2, const float* __restrict__ W3,
               const float* __restrict__ b3, float* __restrict__ Y)
{
    __shared__ __attribute__((aligned(16))) u16 Ah[RT * AST];
    __shared__ __attribute__((aligned(16))) u16 Al[RT * AST];
    __shared__ __attribute__((aligned(16))) u16 h1[RT * H1ST];
    __shared__ float yp[8][RT];

    const int tid  = threadIdx.x;
    const int row0 = blockIdx.x * RT;

    // zero Y tile incl. pad (stale LDS bits could be NaN; NaN*0 = NaN in MFMA)
    {
        short8 z = {0,0,0,0,0,0,0,0};
        for (int i = tid; i < (RT * AST) / 8; i += 512) {
            *(short8*)&Ah[i * 8] = z;
            *(short8*)&Al[i * 8] = z;
        }
    }
    __syncthreads();

    const int w  = tid >> 6, l = tid & 63;
    const int lr = l & 15,  lk = l >> 4;
    const int mg = w;   // phase 1: dim group (32 dims each, W1 read once/block)
    const int cg = w;   // phase 2: col group (16 cols each, W2 read once/block)

    #pragma unroll 1
    for (int v = 0; v < 64; ++v) {
        // ---- per-step parameter prefetch (latency hides under phase-1 MFMAs) ----
        f32x4 b1v[2], w64v[2];
        #pragma unroll
        for (int ni = 0; ni < 2; ++ni) {
            const int dim = mg * 32 + ni * 16 + lk * 4;
            b1v[ni]  = *(const f32x4*)(b1 + v * 256 + dim);
            w64v[ni] = *(const f32x4*)(W1 + ((size_t)v * 65 + 64) * 256 + dim);
        }
        float u_c[2];
        #pragma unroll
        for (int nj = 0; nj < 2; ++nj)
            u_c[nj] = U[(size_t)(row0 + nj * 16 + lr) * 64 + v];
        const float b2c = b2[v * 128 + cg * 16 + lr];
        const float w3c = W3[v * 128 + cg * 16 + lr];

        // ======== Phase 1 — Layer 1 (operand-swapped): h1t[dim][brow] ========
        // wave: dims mg*32..+31 (ni=2) x all 32 rows (nj=2), K=64
        f32x4 acc1[2][2];
        #pragma unroll
        for (int nj = 0; nj < 2; ++nj)
            #pragma unroll
            for (int ni = 0; ni < 2; ++ni) acc1[nj][ni] = (f32x4){0.f, 0.f, 0.f, 0.f};

        #pragma unroll
        for (int kt = 0; kt < 2; ++kt) {
            f16x8 Yfh[2], Yfl[2];
            #pragma unroll
            for (int nj = 0; nj < 2; ++nj) {
                const int o = (nj * 16 + lr) * AST + kt * 32 + lk * 8;
                Yfh[nj] = *(const f16x8*)&Ah[o];
                Yfl[nj] = *(const f16x8*)&Al[o];
            }
            #pragma unroll
            for (int ni = 0; ni < 2; ++ni) {
                const size_t off = (((size_t)(v * 8 + kt * 4 + lk) * 256) + mg * 32 + ni * 16 + lr) << 3;
                const f16x8 Wf = *(const f16x8*)&P1[off];
                #pragma unroll
                for (int nj = 0; nj < 2; ++nj) {
                    acc1[nj][ni] = __builtin_amdgcn_mfma_f32_16x16x32_f16(Wf, Yfh[nj], acc1[nj][ni], 0, 0, 0);
                    acc1[nj][ni] = __builtin_amdgcn_mfma_f32_16x16x32_f16(Wf, Yfl[nj], acc1[nj][ni], 0, 0, 0);
                }
            }
        }
        // epilogue: + bias + u * W1[64,:] (exact fp32), relu, single-fp16 store
        #pragma unroll
        for (int nj = 0; nj < 2; ++nj) {
            const int brow = nj * 16 + lr;
            #pragma unroll
            for (int ni = 0; ni < 2; ++ni) {
                unsigned long long pk = 0;
                #pragma unroll
                for (int r = 0; r < 4; ++r) {
                    float x = acc1[nj][ni][r] + b1v[ni][r] + u_c[nj] * w64v[ni][r];
                    x = fmaxf(x, 0.0f);
                    pk |= ((unsigned long long)f2h(x)) << (16 * r);
                }
                *(unsigned long long*)&h1[brow * H1ST + mg * 32 + ni * 16 + lk * 4] = pk;
            }
        }
        __syncthreads();   // B1: h1 written -> phase 2 may read

        // ======== Phase 2 — Layer 2: h2[32][cg*16..+16], K=256 ========
        f32x4 acc2[2];
        acc2[0] = (f32x4){0.f, 0.f, 0.f, 0.f};
        acc2[1] = (f32x4){0.f, 0.f, 0.f, 0.f};
        #pragma unroll
        for (int kt = 0; kt < 8; ++kt) {
            f16x8 Hf[2];
            #pragma unroll
            for (int mi = 0; mi < 2; ++mi)
                Hf[mi] = *(const f16x8*)&h1[(mi * 16 + lr) * H1ST + kt * 32 + lk * 8];
            const size_t off = (((size_t)(v * 32 + kt * 4 + lk) * 128) + cg * 16 + lr) << 3;
            const f16x8 Bf = *(const f16x8*)&P2[off];
            #pragma unroll
            for (int mi = 0; mi < 2; ++mi)
                acc2[mi] = __builtin_amdgcn_mfma_f32_16x16x32_f16(Hf[mi], Bf, acc2[mi], 0, 0, 0);
        }
        // layer 3 partials in registers: sum over this cg's 16 cols via shfl
        f32x4 sv[2];
        #pragma unroll
        for (int mi = 0; mi < 2; ++mi)
            #pragma unroll
            for (int r = 0; r < 4; ++r) {
                float t = fmaxf(acc2[mi][r] + b2c, 0.0f) * w3c;
                t += __shfl_xor(t, 1);
                t += __shfl_xor(t, 2);
                t += __shfl_xor(t, 4);
                t += __shfl_xor(t, 8);
                sv[mi][r] = t;
            }
        if (lr == 0) {
            *(f32x4*)&yp[cg][lk * 4]      = sv[0];
            *(f32x4*)&yp[cg][16 + lk * 4] = sv[1];
        }
        __syncthreads();   // B2: yp visible; all h1 reads done

        // ======== Phase 3 — finalize y column into the Y tile ========
        if (tid < RT) {
            float y = b3[v];
            #pragma unroll
            for (int c = 0; c < 8; ++c) y += yp[c][tid];
            u16 h = f2h(y);
            Ah[tid * AST + v] = h;
            Al[tid * AST + v] = f2h(y - h2f(h));
        }
        __syncthreads();   // B3: Y col v visible for step v+1; h1 free again
    }

    // ---- final coalesced store (hi+lo reconstruct), 1 float4 per thread ----
    {
        const int row = tid >> 4, c4 = (tid & 15) * 4;
        const u16* hv = &Ah[row * AST + c4];
        const u16* lv = &Al[row * AST + c4];
        float4 o;
        o.x = h2f(hv[0]) + h2f(lv[0]);
        o.y = h2f(hv[1]) + h2f(lv[1]);
        o.z = h2f(hv[2]) + h2f(lv[2]);
        o.w = h2f(hv[3]) + h2f(lv[3]);
        *(float4*)(Y + (size_t)(row0 + row) * 64 + c4) = o;
    }
}

extern "C" void kernel_launch(void* const* d_in, const int* in_sizes, int n_in,
                              void* d_out, int out_size, void* d_ws, size_t ws_size,
                              hipStream_t stream) {
    // inputs: X, U, causal_graph, W1, b1, W2, b2, W3, b3  (X never feeds the recursion)
    const float* U  = (const float*)d_in[1];
    const int*   G  = (const int*)  d_in[2];
    const float* W1 = (const float*)d_in[3];
    const float* b1 = (const float*)d_in[4];
    const float* W2 = (const float*)d_in[5];
    const float* b2 = (const float*)d_in[6];
    const float* W3 = (const float*)d_in[7];
    const float* b3 = (const float*)d_in[8];
    float* Y = (float*)d_out;

    const size_t S1 = (size_t)64 * 64 * 256;     // u16 elements, packed W1
    u16* P1 = (u16*)d_ws;
    u16* P2 = P1 + S1;

    prep_w1<<<(64 * 64 * 256) / 256, 256, 0, stream>>>(W1, G, P1);
    prep_w2<<<(64 * 256 * 128) / 256, 256, 0, stream>>>(W2, P2);
    sen_fused<<<BATCH / RT, 512, 0, stream>>>(U, P1, P2, W1, b1, b2, W3, b3, Y);
}